// Round 11
// baseline (468.060 us; speedup 1.0000x reference)
//
#include <hip/hip_runtime.h>
#include <hip/hip_bf16.h>

#define NUM_EXPERTS 8
#define MODEL_DIM 1024
#define INTER_DIM 4096
#define BM 256
#define BN 256
#define BK 64
// Packed tiles: [rows][64 k] bf16, 16B-chunk XOR swizzle phys_chunk = chunk ^ (row&7),
// baked into DRAM by pack kernels (global_load_lds linear; ds_read applies XOR).
// R9: bank conflicts 11.2M -> 0.

typedef __attribute__((ext_vector_type(8))) short short8;
typedef __attribute__((ext_vector_type(8))) unsigned short ushort8;
typedef __attribute__((ext_vector_type(4))) unsigned short ushort4v;
typedef __attribute__((ext_vector_type(4))) float floatx4;

__device__ __forceinline__ unsigned short f2b(float f) {
  union { float f; unsigned int u; } v; v.f = f;
  unsigned int r = v.u + 0x7fffu + ((v.u >> 16) & 1u);
  return (unsigned short)(r >> 16);
}

#define GLOAD16(g, l)                                                                   \
  __builtin_amdgcn_global_load_lds((const __attribute__((address_space(1))) unsigned int*)(g), \
                                   (__attribute__((address_space(3))) unsigned int*)(l), 16, 0, 0)

// ---------------- router: top-2 + histogram ----------------
__global__ __launch_bounds__(64) void router_kernel(const float* __restrict__ x,
                                                    const float* __restrict__ gw,
                                                    int* __restrict__ eids,
                                                    int* __restrict__ counts, int T) {
  int t = blockIdx.x;
  int lane = threadIdx.x;
  float acc[NUM_EXPERTS];
#pragma unroll
  for (int e = 0; e < NUM_EXPERTS; ++e) acc[e] = 0.f;
  const float* xr = x + (size_t)t * MODEL_DIM;
#pragma unroll 4
  for (int i = lane; i < MODEL_DIM; i += 64) {
    float xv = xr[i];
#pragma unroll
    for (int e = 0; e < NUM_EXPERTS; ++e) acc[e] += xv * gw[e * MODEL_DIM + i];
  }
#pragma unroll
  for (int e = 0; e < NUM_EXPERTS; ++e) {
    float v = acc[e];
#pragma unroll
    for (int off = 32; off > 0; off >>= 1) v += __shfl_xor(v, off);
    acc[e] = v;
  }
  if (lane == 0) {
    int e0 = 0; float b0 = acc[0];
#pragma unroll
    for (int e = 1; e < NUM_EXPERTS; ++e) if (acc[e] > b0) { b0 = acc[e]; e0 = e; }
    int e1 = -1; float b1 = -3.4e38f;
#pragma unroll
    for (int e = 0; e < NUM_EXPERTS; ++e) if (e != e0 && acc[e] > b1) { b1 = acc[e]; e1 = e; }
    eids[t] = e0;
    eids[T + t] = e1;
    atomicAdd(&counts[e0], 1);
    atomicAdd(&counts[e1], 1);
  }
}

// ---------------- offsets + padded offsets + balanced work lists ----------------
__global__ void offsets_kernel(const int* __restrict__ counts, int* __restrict__ offsets,
                               int* __restrict__ cursor, int* __restrict__ poff,
                               int* __restrict__ wu, int* __restrict__ wd,
                               int* __restrict__ wcnt) {
  if (threadIdx.x == 0 && blockIdx.x == 0) {
    int s = 0, ps = 0;
    for (int e = 0; e < NUM_EXPERTS; ++e) {
      offsets[e] = s; cursor[e] = s; poff[e] = ps;
      s += counts[e];
      ps += ((counts[e] + 127) >> 7) << 7;
    }
    offsets[NUM_EXPERTS] = s;
    poff[NUM_EXPERTS] = ps;
    // UP items: expert-fastest => blockIdx&7 ~ e (XCD affinity) while balanced.
    int nu = 0;
    for (int n = 0; n < 16; ++n)
      for (int mt = 0; mt < 16; ++mt)
        for (int e = 0; e < NUM_EXPERTS; ++e)
          if (mt * 256 < counts[e]) wu[nu++] = e | (mt << 3) | (n << 8);
    int nd = 0;
    for (int ks = 0; ks < 4; ++ks)
      for (int n = 0; n < 4; ++n)
        for (int mt = 0; mt < 16; ++mt)
          for (int e = 0; e < NUM_EXPERTS; ++e)
            if (mt * 256 < counts[e]) wd[nd++] = e | (mt << 3) | (n << 8) | (ks << 12);
    wcnt[0] = nu; wcnt[1] = nd;
  }
}

__global__ void scatter_kernel(const int* __restrict__ eids, int* __restrict__ cursor,
                               int* __restrict__ token_list, int T) {
  int i = blockIdx.x * blockDim.x + threadIdx.x;
  if (i < 2 * T) {
    int e = eids[i];
    int pos = atomicAdd(&cursor[e], 1);
    int t = (i >= T) ? (i - T) : i;
    token_list[pos] = t;
  }
}

// ---------------- fused pack: gather-x | wconv-up | wconv-dn (range-decoded) ----------
// gather: xg half-tiles [p/128][kt16][128][64] swizzled, zero pads. 16 rows/block.
// wconv: W [E][K][N] fp32 -> swizzled [256 n][64 k] bf16 tiles; 2x 64x64 tiles/block.
__global__ __launch_bounds__(512) void pack_kernel(
    const float* __restrict__ X, const float* __restrict__ Wup, const float* __restrict__ Wdn,
    unsigned short* __restrict__ xg, unsigned short* __restrict__ wTu,
    unsigned short* __restrict__ wTd,
    const int* __restrict__ offsets, const int* __restrict__ poff,
    const int* __restrict__ token_list, int g_end, int u_end) {
  __shared__ unsigned short tile[2][64 * 68];
  const int b = blockIdx.x;
  const int tid = threadIdx.x;
  if (b < g_end) {
    const int p = b * 16 + (tid >> 5);
    const int kb = tid & 31;
    if (p >= poff[NUM_EXPERTS]) return;
    int e = 0;
#pragma unroll
    for (int q = 1; q < NUM_EXPERTS; ++q) if (p >= poff[q]) e = q;
    const int local = p - poff[e];
    const int cnt = offsets[e + 1] - offsets[e];
    const int row = p & 127;
    const int r7 = row & 7;
    unsigned short* dst = xg + ((size_t)(p >> 7) * 16 + (kb >> 1)) * 8192 + row * 64;
    const int lc0 = (kb & 1) * 4;
    if (local < cnt) {
      const int tok = token_list[offsets[e] + local];
      const float* src = X + (size_t)tok * MODEL_DIM + kb * 32;
#pragma unroll
      for (int cc = 0; cc < 4; ++cc) {
        float4 v0 = *(const float4*)(src + cc * 8);
        float4 v1 = *(const float4*)(src + cc * 8 + 4);
        ushort8 s;
        s[0] = f2b(v0.x); s[1] = f2b(v0.y); s[2] = f2b(v0.z); s[3] = f2b(v0.w);
        s[4] = f2b(v1.x); s[5] = f2b(v1.y); s[6] = f2b(v1.z); s[7] = f2b(v1.w);
        *(ushort8*)(dst + (((lc0 + cc) ^ r7) << 3)) = s;
      }
    } else {
      const ushort8 z = {0, 0, 0, 0, 0, 0, 0, 0};
#pragma unroll
      for (int cc = 0; cc < 4; ++cc) *(ushort8*)(dst + (((lc0 + cc) ^ r7) << 3)) = z;
    }
    return;
  }
  // wconv ranges
  const float* W; unsigned short* O; int K, N, t;
  const int sb = tid >> 8;
  const int ltid = tid & 255;
  if (b < u_end) { W = Wup; O = wTu; K = MODEL_DIM;  N = INTER_DIM; t = (b - g_end) * 2 + sb; }
  else           { W = Wdn; O = wTd; K = INTER_DIM; N = MODEL_DIM;  t = (b - u_end) * 2 + sb; }
  const int KT = K >> 6, NT = N >> 6;
  const int e = t / (KT * NT);
  const int rem = t % (KT * NT);
  const int n0 = (rem % NT) * 64;
  const int k0 = (rem / NT) * 64;
  const float* src = W + (size_t)e * K * N;
  {
    const int kr = ltid >> 2;
    const int nq = (ltid & 3) * 16;
    const float* p = src + (size_t)(k0 + kr) * N + n0 + nq;
#pragma unroll
    for (int j = 0; j < 4; ++j) {
      float4 v = *(const float4*)(p + j * 4);
      ushort4v s;
      s[0] = f2b(v.x); s[1] = f2b(v.y); s[2] = f2b(v.z); s[3] = f2b(v.w);
      *(ushort4v*)(&tile[sb][kr * 68 + nq + j * 4]) = s;
    }
  }
  __syncthreads();
  {
    const int NT2 = N >> 8, KT2 = K >> 6;
    const int nl = ltid >> 2;
    const int n = n0 + nl;
    const int r7 = n & 7;
    const int ks2 = (ltid & 3) * 16;
#pragma unroll
    for (int c = 0; c < 4; ++c) {
      const int tk = k0 + ks2 + c * 4;
      const int ktl = tk & 63;
      ushort4v s;
      s[0] = tile[sb][(ks2 + c * 4 + 0) * 68 + nl];
      s[1] = tile[sb][(ks2 + c * 4 + 1) * 68 + nl];
      s[2] = tile[sb][(ks2 + c * 4 + 2) * 68 + nl];
      s[3] = tile[sb][(ks2 + c * 4 + 3) * 68 + nl];
      unsigned short* q = O + ((size_t)(e * NT2 + (n >> 8)) * KT2 + (tk >> 6)) * 16384 +
                          (n & 255) * 64 + ((((ktl >> 3) ^ r7)) << 3) + (ktl & 7);
      *(ushort4v*)q = s;
    }
  }
}

// ---------------- grouped GEMM, 256x256, BK=64, work-list balanced ----------
#define STAGE(CUR, S) {                                                    \
  _Pragma("unroll")                                                        \
  for (int q = 0; q < 4; ++q)                                              \
    GLOAD16(aSrcW + (size_t)(S) * 8192 + q * 512, &sA[CUR][w * 2048 + q * 512]);  \
  _Pragma("unroll")                                                        \
  for (int q = 0; q < 4; ++q)                                              \
    GLOAD16(bSrcW + (size_t)(S) * 16384 + q * 512, &sB[CUR][w * 2048 + q * 512]); \
}

template <bool UP>
__global__ __launch_bounds__(512) void moe_gemm(
    const unsigned short* __restrict__ A,
    const unsigned short* __restrict__ Bw,
    unsigned short* __restrict__ Hout,
    float* __restrict__ Out,
    const int* __restrict__ offsets,
    const int* __restrict__ poff,
    const int* __restrict__ token_list,
    const int* __restrict__ wl,
    const int* __restrict__ wcnt) {
  constexpr int NSTEP = 16;

  if ((int)blockIdx.x >= wcnt[UP ? 0 : 1]) return;
  const int it = wl[blockIdx.x];
  const int e = it & 7;
  const int m_idx = (it >> 3) & 31;
  const int n_idx = (it >> 8) & 15;
  const int ks = (it >> 12) & 3;

  const int off = offsets[e];
  const int cnt = offsets[e + 1] - off;
  const int m0 = m_idx * BM;
  const int n0 = n_idx * BN;
  const int pe0 = poff[e];
  const int pcnt = poff[e + 1] - pe0;
  const int pm0 = pe0 + m0;
  const int rt0 = pm0 >> 7;
  const int rt1 = (m0 + 128 < pcnt) ? rt0 + 1 : rt0;

  __shared__ unsigned short sA[2][BM * BK];
  __shared__ unsigned short sB[2][BN * BK];

  const int tid = threadIdx.x;
  const int lane = tid & 63;
  const int w = tid >> 6;
  const int wm = w >> 2;
  const int wn = w & 3;
  const int fr = lane & 15;
  const int fr7 = fr & 7;
  const int csel = lane >> 4;

  const unsigned short* aB0;
  const unsigned short* aB1;
  const unsigned short* bB;
  if constexpr (UP) {
    aB0 = A + (size_t)(rt0 * 16) * 8192;
    aB1 = A + (size_t)(rt1 * 16) * 8192;
    bB = Bw + (size_t)((e * 16 + n_idx) * 16) * 16384;
  } else {
    aB0 = A + (size_t)(rt0 * 64 + ks * 16) * 8192;
    aB1 = A + (size_t)(rt1 * 64 + ks * 16) * 8192;
    bB = Bw + (size_t)((e * 4 + n_idx) * 64 + ks * 16) * 16384;
  }
  const unsigned short* aSrcW = (w < 4 ? aB0 : aB1) + (w & 3) * 2048 + lane * 8;
  const unsigned short* bSrcW = bB + w * 2048 + lane * 8;

  floatx4 acc[8][4];
  const floatx4 zero = {0.f, 0.f, 0.f, 0.f};
#pragma unroll
  for (int i = 0; i < 8; ++i)
#pragma unroll
    for (int j = 0; j < 4; ++j) acc[i][j] = zero;

  STAGE(0, 0)

  int cur = 0;
  for (int s = 0; s < NSTEP; ++s) {
    if (s + 1 < NSTEP) {
      STAGE(cur ^ 1, s + 1)                              // 16 outstanding
      asm volatile("s_waitcnt vmcnt(8)" ::: "memory");   // this step's 8 landed
    } else {
      asm volatile("s_waitcnt vmcnt(0)" ::: "memory");
    }
    __builtin_amdgcn_s_barrier();

#pragma unroll
    for (int kk = 0; kk < 2; ++kk) {
      const int cofs = (((kk << 2) + csel) ^ fr7) << 3;  // T2 swizzle
      short8 a[8], bq[4];
#pragma unroll
      for (int i = 0; i < 8; ++i)
        a[i] = *(const short8*)(&sA[cur][(wm * 128 + i * 16 + fr) * 64 + cofs]);
#pragma unroll
      for (int j = 0; j < 4; ++j)
        bq[j] = *(const short8*)(&sB[cur][(wn * 64 + j * 16 + fr) * 64 + cofs]);
      __builtin_amdgcn_s_setprio(1);
#pragma unroll
      for (int i = 0; i < 8; ++i)
#pragma unroll
        for (int j = 0; j < 4; ++j)
          acc[i][j] = __builtin_amdgcn_mfma_f32_16x16x32_bf16(a[i], bq[j], acc[i][j], 0, 0, 0);
      __builtin_amdgcn_s_setprio(0);
    }

    __builtin_amdgcn_s_barrier();
    cur ^= 1;
  }

  const int rsub = (lane >> 4) * 4;
#pragma unroll
  for (int i = 0; i < 8; ++i) {
#pragma unroll
    for (int j = 0; j < 4; ++j) {
#pragma unroll
      for (int jj = 0; jj < 4; ++jj) {
        const int r = wm * 128 + i * 16 + rsub + jj;
        const int c = wn * 64 + j * 16 + fr;
        if (m0 + r < cnt) {
          if constexpr (UP) {
            const int pr = pm0 + r;
            const int gc = n0 + c;
            const int row = pr & 127;
            const int kt = gc & 63;
            Hout[((size_t)(pr >> 7) * 64 + (gc >> 6)) * 8192 + row * 64 +
                 ((((kt >> 3) ^ (row & 7))) << 3) + (kt & 7)] = f2b(acc[i][j][jj]);
          } else {
            const int t = token_list[off + m0 + r];
            atomicAdd(&Out[(size_t)t * MODEL_DIM + n0 + c], acc[i][j][jj]);
          }
        }
      }
    }
  }
}

extern "C" void kernel_launch(void* const* d_in, const int* in_sizes, int n_in,
                              void* d_out, int out_size, void* d_ws, size_t ws_size,
                              hipStream_t stream) {
  const float* x = (const float*)d_in[0];
  const float* gw = (const float*)d_in[1];
  const float* w_up = (const float*)d_in[2];
  const float* w_down = (const float*)d_in[3];
  float* out = (float*)d_out;

  const int T = in_sizes[0] / MODEL_DIM;  // 2048
  const int total = 2 * T;                // 4096

  char* wsb = (char*)d_ws;
  int* eids = (int*)wsb;            // [4096]
  int* counts = eids + 4096;        // [8]
  int* offsets = counts + 8;        // [9]+pad
  int* cursor = offsets + 12;       // [8]
  int* poff = cursor + 8;           // [9]+pad
  int* wcnt = poff + 12;            // [2]+pad
  int* wu = wcnt + 4;               // [512]
  int* wd = wu + 512;               // [512]
  int* token_list = wd + 512;       // [4096]
  unsigned short* xg  = (unsigned short*)(wsb + (1ULL << 20));    // 10 MiB (<=5112 rows)
  unsigned short* h   = (unsigned short*)(wsb + (11ULL << 20));   // 40 MiB
  unsigned short* wTu = (unsigned short*)(wsb + (51ULL << 20));   // 64 MiB (ends 115 MiB, proven)
  unsigned short* wTd = (unsigned short*)(wsb + (115ULL << 20));  // 64 MiB (gated)
  const bool gate = ws_size >= (179ULL << 20);
  unsigned short* wTdn = gate ? wTd : wTu;

  hipMemsetAsync(counts, 0, NUM_EXPERTS * sizeof(int), stream);
  hipMemsetAsync(d_out, 0, (size_t)out_size * sizeof(float), stream);

  router_kernel<<<T, 64, 0, stream>>>(x, gw, eids, counts, T);
  offsets_kernel<<<1, 64, 0, stream>>>(counts, offsets, cursor, poff, wu, wd, wcnt);
  scatter_kernel<<<(total + 255) / 256, 256, 0, stream>>>(eids, cursor, token_list, T);

  // pack dispatch 1: gather (320) + wconv_up (4096) [+ wconv_dn (4096) if gate]
  const int GEND = 320;
  const int UEND = GEND + 4096;
  const int grid1 = gate ? (UEND + 4096) : UEND;
  pack_kernel<<<grid1, 512, 0, stream>>>(x, w_up, w_down, xg, wTu, wTdn,
                                         offsets, poff, token_list, GEND, UEND);

  moe_gemm<true><<<368, 512, 0, stream>>>(xg, wTu, h, nullptr,
                                          offsets, poff, token_list, wu, wcnt);

  if (!gate) {  // serial wconv_dn into shared buffer
    pack_kernel<<<4096, 512, 0, stream>>>(x, w_up, w_down, xg, wTu, wTu,
                                          offsets, poff, token_list, 0, 0);
  }

  moe_gemm<false><<<368, 512, 0, stream>>>(h, wTdn, nullptr, out,
                                           offsets, poff, token_list, wd, wcnt);
}